// Round 7
// baseline (49.173 us; speedup 1.0000x reference)
//
#include <hip/hip_runtime.h>
#include <math.h>

// x: (8,16,512,64) fp32; flat = [wk | wq], each (64,4). Output: int32 top-12 idx.
constexpr int kDIn  = 64;
constexpr int kN    = 512;
constexpr int kTopK = 12;
constexpr int kNBt  = 128;          // 8*16
// exp(SCALE*h) = exp2(CEXP*h); SCALE = 0.125; CEXP = SCALE*log2(e)
#define CEXP 0.18033688f
#define EXP2(v) __builtin_amdgcn_exp2f(v)
// NUMERIC INVARIANT (R3/R5 post-mortems): every exp2 argument <= 0 via EXACT
// row max. Terms in [0,1], l in [1,512], r in [2^-9,1] -- no denormal, no inf,
// immune to FTZ. Approximate shifts (CS bound, fixed -128) both produced
// inf/NaN tiles (FTZ: l flushed to 0 -> r = inf).

#define DOT4(k, q)        fmaf((k).x,(q).x, fmaf((k).y,(q).y, fmaf((k).z,(q).z, (k).w*(q).w)))
#define DOT4A(k, q, add)  fmaf((k).x,(q).x, fmaf((k).y,(q).y, fmaf((k).z,(q).z, fmaf((k).w,(q).w,(add)))))

// ws: apart [256][512] floats (partial column scores per (bt, row-half))
constexpr size_t kWsFloats = (size_t)kNBt * 2 * kN;

// ============ KA: fused projection + rowstats + colsum ============
// grid 256 (bt*2 + h), block 512. Block handles row-half h of tile bt:
//   phase1: project all 512 Q rows + my 256 K rows (CEXP-scaled) -> LDS
//   phase2: exact row max + exp-sum for my rows (2 thr/row, j-halves, merged)
//   phase3: my rows' contribution to all 512 column scores -> apart
__global__ __launch_bounds__(512) void fused_attn_kernel(
    const float* __restrict__ x, const float* __restrict__ flat,
    float* __restrict__ apart)
{
  __shared__ float4 Wk[kDIn];
  __shared__ float4 Wq[kDIn];
  __shared__ float4 Qs[kN];      // unscaled Q, all 512 rows
  __shared__ float4 Ks[256];     // CEXP-scaled K, my half
  __shared__ float2 Pp[kN];      // per-thread (m, l) row partials
  __shared__ float2 Sc[256];     // merged (m, 1/l) per row of my half

  const int tid = threadIdx.x;
  const int bt  = blockIdx.x >> 1;
  const int h   = blockIdx.x & 1;

  if (tid < 64)       Wk[tid]      = reinterpret_cast<const float4*>(flat)[tid];
  else if (tid < 128) Wq[tid - 64] = reinterpret_cast<const float4*>(flat)[tid];
  __syncthreads();

  // ---- phase 1: thread t projects row t (proven R1 inner loop) ----
  {
    const float4* xr4 = reinterpret_cast<const float4*>(x + ((size_t)bt * kN + tid) * kDIn);
    float k0=0.f,k1=0.f,k2=0.f,k3=0.f, q0=0.f,q1=0.f,q2=0.f,q3=0.f;
#pragma unroll
    for (int cc = 0; cc < kDIn / 4; ++cc) {
      float4 xv = xr4[cc];
#pragma unroll
      for (int u = 0; u < 4; ++u) {
        float v = (u==0)?xv.x:(u==1)?xv.y:(u==2)?xv.z:xv.w;
        float4 a = Wk[cc*4+u];
        float4 b = Wq[cc*4+u];
        k0 = fmaf(v, a.x, k0); k1 = fmaf(v, a.y, k1);
        k2 = fmaf(v, a.z, k2); k3 = fmaf(v, a.w, k3);
        q0 = fmaf(v, b.x, q0); q1 = fmaf(v, b.y, q1);
        q2 = fmaf(v, b.z, q2); q3 = fmaf(v, b.w, q3);
      }
    }
    Qs[tid] = make_float4(q0, q1, q2, q3);
    if ((tid >> 8) == h)
      Ks[tid & 255] = make_float4(CEXP*k0, CEXP*k1, CEXP*k2, CEXP*k3);
  }
  __syncthreads();

  // ---- phase 2: rowstats; thread = (jh = tid>>8, row = h*256 + (tid&255)) ----
  // qb is wave-uniform (waves 0-3: jh=0, waves 4-7: jh=1) -> broadcast reads.
  {
    const float4 k = Ks[tid & 255];
    const float4* qb = &Qs[(tid >> 8) << 8];

    float m0 = -INFINITY, m1 = -INFINITY;
#pragma unroll 4
    for (int j = 0; j < 256; j += 2) {
      float4 qa = qb[j], qc = qb[j+1];
      m0 = fmaxf(m0, DOT4(k, qa));
      m1 = fmaxf(m1, DOT4(k, qc));
    }
    const float m = fmaxf(m0, m1);

    float l0 = 0.f, l1 = 0.f;
#pragma unroll 4
    for (int j = 0; j < 256; j += 2) {
      float4 qa = qb[j], qc = qb[j+1];
      l0 += EXP2(DOT4A(k, qa, -m));
      l1 += EXP2(DOT4A(k, qc, -m));
    }
    Pp[tid] = make_float2(m, l0 + l1);
  }
  __syncthreads();
  if (tid < 256) {
    float2 p0 = Pp[tid];
    float2 p1 = Pp[tid + 256];
    float m = fmaxf(p0.x, p1.x);
    float l = fmaf(p0.y, EXP2(p0.x - m), p1.y * EXP2(p1.x - m));
    Sc[tid] = make_float2(m, 1.0f / l);
  }
  __syncthreads();

  // ---- phase 3: thread = column tid; sum my 256 rows' softmax weights ----
  {
    const float4 q = Qs[tid];
    float a0 = 0.f, a1 = 0.f;
#pragma unroll 4
    for (int i = 0; i < 256; i += 2) {
      float4 ka = Ks[i], kb = Ks[i+1];
      float2 s0 = Sc[i], s1 = Sc[i+1];
      a0 = fmaf(EXP2(DOT4A(q, ka, -s0.x)), s0.y, a0);
      a1 = fmaf(EXP2(DOT4A(q, kb, -s1.x)), s1.y, a1);
    }
    apart[(size_t)blockIdx.x * kN + tid] = a0 + a1;
  }
}

// ============ KB: add 2 partials + top-12; grid 128, block 64 ============
__global__ __launch_bounds__(64) void topk_kernel(
    const float* __restrict__ apart, int* __restrict__ out)
{
  const int lane = threadIdx.x;
  const int bt   = blockIdx.x;
  const float4* p0 = reinterpret_cast<const float4*>(apart + (size_t)(bt*2)     * kN);
  const float4* p1 = reinterpret_cast<const float4*>(apart + (size_t)(bt*2 + 1) * kN);

  float4 u0 = p0[lane*2], u1 = p0[lane*2+1];
  float4 w0 = p1[lane*2], w1 = p1[lane*2+1];
  float v[8];
  v[0]=u0.x+w0.x; v[1]=u0.y+w0.y; v[2]=u0.z+w0.z; v[3]=u0.w+w0.w;
  v[4]=u1.x+w1.x; v[5]=u1.y+w1.y; v[6]=u1.z+w1.z; v[7]=u1.w+w1.w;

  for (int rnd = 0; rnd < kTopK; ++rnd) {
    float bv = v[0];
    int   bi = lane * 8;
#pragma unroll
    for (int r = 1; r < 8; ++r) {
      if (v[r] > bv) { bv = v[r]; bi = lane * 8 + r; }
    }
#pragma unroll
    for (int off = 32; off >= 1; off >>= 1) {
      float ov = __shfl_xor(bv, off);
      int   oi = __shfl_xor(bi, off);
      if (ov > bv || (ov == bv && oi < bi)) { bv = ov; bi = oi; }
    }
    if (lane == 0) out[bt * kTopK + rnd] = bi;
#pragma unroll
    for (int r = 0; r < 8; ++r) {
      if (lane * 8 + r == bi) v[r] = -INFINITY;
    }
  }
}

// ============ fallback: round-1 single kernel (used only if ws too small) ============
__global__ __launch_bounds__(512, 1) void sparse_attn_topk_fallback(
    const float* __restrict__ x, const float* __restrict__ flat, int* __restrict__ out)
{
  __shared__ float4 wk4[kDIn];
  __shared__ float4 wq4[kDIn];
  __shared__ float4 Ks[kN];
  __shared__ float4 Qs[kN];
  __shared__ float  Ms[kN];
  __shared__ float  Rl[kN];
  __shared__ float  As[kN];

  const int tid = threadIdx.x;
  const int bt  = blockIdx.x;

  if (tid < 64)       wk4[tid]      = reinterpret_cast<const float4*>(flat)[tid];
  else if (tid < 128) wq4[tid - 64] = reinterpret_cast<const float4*>(flat)[tid];
  __syncthreads();

  const float* xr = x + ((size_t)bt * kN + tid) * kDIn;
  float k0=0.f,k1=0.f,k2=0.f,k3=0.f, q0=0.f,q1=0.f,q2=0.f,q3=0.f;
#pragma unroll
  for (int c = 0; c < kDIn; ++c) {
    float xv = xr[c];
    float4 a = wk4[c];
    float4 b = wq4[c];
    k0 = fmaf(xv, a.x, k0); k1 = fmaf(xv, a.y, k1);
    k2 = fmaf(xv, a.z, k2); k3 = fmaf(xv, a.w, k3);
    q0 = fmaf(xv, b.x, q0); q1 = fmaf(xv, b.y, q1);
    q2 = fmaf(xv, b.z, q2); q3 = fmaf(xv, b.w, q3);
  }
  Ks[tid] = make_float4(k0, k1, k2, k3);
  Qs[tid] = make_float4(q0, q1, q2, q3);
  __syncthreads();

  float m = -INFINITY;
#pragma unroll 8
  for (int j = 0; j < kN; ++j) {
    float4 qj = Qs[j];
    float h = fmaf(k0, qj.x, fmaf(k1, qj.y, fmaf(k2, qj.z, k3 * qj.w)));
    m = fmaxf(m, h);
  }
  float l = 0.f;
#pragma unroll 8
  for (int j = 0; j < kN; ++j) {
    float4 qj = Qs[j];
    float h = fmaf(k0, qj.x, fmaf(k1, qj.y, fmaf(k2, qj.z, k3 * qj.w)));
    l += exp2f(CEXP * (h - m));
  }
  Ms[tid] = m;
  Rl[tid] = 1.0f / l;
  __syncthreads();

  float acc = 0.f;
#pragma unroll 8
  for (int i = 0; i < kN; ++i) {
    float4 ki = Ks[i];
    float h = fmaf(q0, ki.x, fmaf(q1, ki.y, fmaf(q2, ki.z, q3 * ki.w)));
    acc += exp2f(CEXP * (h - Ms[i])) * Rl[i];
  }
  As[tid] = acc;
  __syncthreads();

  if (tid < 64) {
    float v[8];
#pragma unroll
    for (int r = 0; r < 8; ++r) v[r] = As[tid * 8 + r];
    for (int rnd = 0; rnd < kTopK; ++rnd) {
      float bv = v[0];
      int   bi = tid * 8;
#pragma unroll
      for (int r = 1; r < 8; ++r)
        if (v[r] > bv) { bv = v[r]; bi = tid * 8 + r; }
#pragma unroll
      for (int off = 32; off >= 1; off >>= 1) {
        float ov = __shfl_xor(bv, off);
        int   oi = __shfl_xor(bi, off);
        if (ov > bv || (ov == bv && oi < bi)) { bv = ov; bi = oi; }
      }
      if (tid == 0) out[bt * kTopK + rnd] = bi;
#pragma unroll
      for (int r = 0; r < 8; ++r)
        if (tid * 8 + r == bi) v[r] = -INFINITY;
    }
  }
}

extern "C" void kernel_launch(void* const* d_in, const int* in_sizes, int n_in,
                              void* d_out, int out_size, void* d_ws, size_t ws_size,
                              hipStream_t stream) {
  const float* x    = (const float*)d_in[0];
  const float* flat = (const float*)d_in[1];
  int* out = (int*)d_out;

  if (ws_size < kWsFloats * sizeof(float)) {
    sparse_attn_topk_fallback<<<kNBt, kN, 0, stream>>>(x, flat, out);
    return;
  }
  float* apart = (float*)d_ws;
  fused_attn_kernel<<<kNBt * 2, 512, 0, stream>>>(x, flat, apart);
  topk_kernel      <<<kNBt,      64, 0, stream>>>(apart, out);
}

// Round 8
// 39.032 us; speedup vs baseline: 1.2598x; 1.2598x over previous
//
#include <hip/hip_runtime.h>
#include <math.h>

// x: (8,16,512,64) fp32; flat = [wk | wq], each (64,4). Output: int32 top-12 idx.
constexpr int kDIn  = 64;
constexpr int kN    = 512;
constexpr int kTopK = 12;
constexpr int kNBt  = 128;          // 8*16
// exp(SCALE*h) = exp2(CEXP*h); SCALE = 0.125; CEXP = SCALE*log2(e)
#define CEXP 0.18033688f
#define EXP2(v) __builtin_amdgcn_exp2f(v)
#define LOG2F(v) __builtin_amdgcn_logf(v)       // v_log_f32 = log base 2
// NUMERIC INVARIANT (R3/R5): every exp2 argument <= 0 via a true running/exact
// row max. Online variant: l >= 1 after each chunk (current-max term = 1);
// rescale factor exp2(m_old-m_new) <= 1 (underflow benign). No denormal/inf.

#define DOT4(k, q)        fmaf((k).x,(q).x, fmaf((k).y,(q).y, fmaf((k).z,(q).z, (k).w*(q).w)))
#define DOT4A(k, q, add)  fmaf((k).x,(q).x, fmaf((k).y,(q).y, fmaf((k).z,(q).z, fmaf((k).w,(q).w,(add)))))

// ws: apart [128][4][512] floats
constexpr size_t kWsFloats = (size_t)kNBt * 4 * kN;

// ============ KA: fused projection + online rowstats + colsum partial ============
// grid 512, block 512. Logical (tile, s): block owns 128 K-rows [s*128, s*128+128).
// XCD swizzle: physical p = (tile%8) + 8*s + 32*(tile/8) -> same-tile blocks on
// one XCD (shared L2 for the 4x-read x tile). Inverse below.
__global__ __launch_bounds__(512, 4) void fused_attn_kernel(
    const float* __restrict__ x, const float* __restrict__ flat,
    float* __restrict__ apart)
{
  __shared__ float4 Wk[kDIn];
  __shared__ float4 Wq[kDIn];
  __shared__ float4 Qs[kN];        // unscaled Q, all 512 rows   (8 KB)
  __shared__ float4 Ks[128];       // CEXP-scaled K, own quarter (2 KB)
  __shared__ float2 Pp[kN];        // (m, l) partials per (row, j-slice)
  __shared__ __align__(16) float Cs[128];  // c_i = m_i + log2(l_i)

  const int tid = threadIdx.x;
  const int p   = blockIdx.x;
  const int xcd = p & 7;
  const int rem = p >> 3;
  const int s    = rem & 3;
  const int tile = ((rem >> 2) << 3) | xcd;

  if (tid < 64)       Wk[tid]      = reinterpret_cast<const float4*>(flat)[tid];
  else if (tid < 128) Wq[tid - 64] = reinterpret_cast<const float4*>(flat)[tid];
  __syncthreads();

  // ---- phase 1: thread t projects row t. Q always; K only for own quarter ----
  {
    const float4* xr4 = reinterpret_cast<const float4*>(x + ((size_t)tile * kN + tid) * kDIn);
    float q0=0.f,q1=0.f,q2=0.f,q3=0.f;
    if ((tid >> 7) == s) {
      float k0=0.f,k1=0.f,k2=0.f,k3=0.f;
#pragma unroll
      for (int cc = 0; cc < kDIn / 4; ++cc) {
        float4 xv = xr4[cc];
#pragma unroll
        for (int u = 0; u < 4; ++u) {
          float v = (u==0)?xv.x:(u==1)?xv.y:(u==2)?xv.z:xv.w;
          float4 a = Wk[cc*4+u];
          float4 b = Wq[cc*4+u];
          k0 = fmaf(v, a.x, k0); k1 = fmaf(v, a.y, k1);
          k2 = fmaf(v, a.z, k2); k3 = fmaf(v, a.w, k3);
          q0 = fmaf(v, b.x, q0); q1 = fmaf(v, b.y, q1);
          q2 = fmaf(v, b.z, q2); q3 = fmaf(v, b.w, q3);
        }
      }
      Ks[tid & 127] = make_float4(CEXP*k0, CEXP*k1, CEXP*k2, CEXP*k3);
    } else {
#pragma unroll
      for (int cc = 0; cc < kDIn / 4; ++cc) {
        float4 xv = xr4[cc];
#pragma unroll
        for (int u = 0; u < 4; ++u) {
          float v = (u==0)?xv.x:(u==1)?xv.y:(u==2)?xv.z:xv.w;
          float4 b = Wq[cc*4+u];
          q0 = fmaf(v, b.x, q0); q1 = fmaf(v, b.y, q1);
          q2 = fmaf(v, b.z, q2); q3 = fmaf(v, b.w, q3);
        }
      }
    }
    Qs[tid] = make_float4(q0, q1, q2, q3);
  }
  __syncthreads();

  // ---- phase 2: ONLINE rowstats. thread = (row = tid&127, js = tid>>7) ----
  // j-slice [js*128, js*128+128); js is wave-uniform -> Qs reads broadcast.
  {
    const float4 k = Ks[tid & 127];
    const float4* qb = &Qs[(tid >> 7) << 7];

    float m = -INFINITY, l0 = 0.f, l1 = 0.f;
#pragma unroll 2
    for (int c = 0; c < 128; c += 8) {
      float4 qa = qb[c],   qb_ = qb[c+1], qc = qb[c+2], qd = qb[c+3];
      float4 qe = qb[c+4], qf  = qb[c+5], qg = qb[c+6], qh = qb[c+7];
      float h0 = DOT4(k, qa),  h1 = DOT4(k, qb_), h2 = DOT4(k, qc), h3 = DOT4(k, qd);
      float h4 = DOT4(k, qe),  h5 = DOT4(k, qf),  h6 = DOT4(k, qg), h7 = DOT4(k, qh);
      float cm = fmaxf(fmaxf(fmaxf(h0,h1), fmaxf(h2,h3)),
                       fmaxf(fmaxf(h4,h5), fmaxf(h6,h7)));
      if (cm > m) {           // rare after warm-up; factor <= 1 (underflow benign)
        float f = EXP2(m - cm);
        l0 *= f; l1 *= f; m = cm;
      }
      l0 += EXP2(h0 - m); l1 += EXP2(h1 - m);
      l0 += EXP2(h2 - m); l1 += EXP2(h3 - m);
      l0 += EXP2(h4 - m); l1 += EXP2(h5 - m);
      l0 += EXP2(h6 - m); l1 += EXP2(h7 - m);
    }
    Pp[tid] = make_float2(m, l0 + l1);
  }
  __syncthreads();
  if (tid < 128) {
    float2 a = Pp[tid], b = Pp[tid+128], c = Pp[tid+256], d = Pp[tid+384];
    float m = fmaxf(fmaxf(a.x, b.x), fmaxf(c.x, d.x));
    float l = fmaf(a.y, EXP2(a.x - m), b.y * EXP2(b.x - m)) +
              fmaf(c.y, EXP2(c.x - m), d.y * EXP2(d.x - m));
    Cs[tid] = m + LOG2F(l);       // l in [1,512] -> log2 in [0,9.01]
  }
  __syncthreads();

  // ---- phase 3: thread = column tid; own 128 rows' softmax weights ----
  {
    const float4 q = Qs[tid];
    float a0 = 0.f, a1 = 0.f;
#pragma unroll 4
    for (int i = 0; i < 128; i += 4) {
      float4 k0 = Ks[i], k1 = Ks[i+1], k2 = Ks[i+2], k3 = Ks[i+3];
      float4 cc = *reinterpret_cast<const float4*>(&Cs[i]);
      a0 += EXP2(DOT4A(q, k0, -cc.x));
      a1 += EXP2(DOT4A(q, k1, -cc.y));
      a0 += EXP2(DOT4A(q, k2, -cc.z));
      a1 += EXP2(DOT4A(q, k3, -cc.w));
    }
    apart[((size_t)tile * 4 + s) * kN + tid] = a0 + a1;
  }
}

// ============ KB: sum 4 partials + top-12; grid 128, block 64 ============
__global__ __launch_bounds__(64) void topk_kernel(
    const float* __restrict__ apart, int* __restrict__ out)
{
  const int lane = threadIdx.x;
  const int bt   = blockIdx.x;
  const float* P = apart + (size_t)bt * 4 * kN;

  float v[8];
  {
    float4 acc0 = make_float4(0.f,0.f,0.f,0.f);
    float4 acc1 = make_float4(0.f,0.f,0.f,0.f);
#pragma unroll
    for (int s = 0; s < 4; ++s) {
      const float4* Ps = reinterpret_cast<const float4*>(P + s * kN);
      float4 u0 = Ps[lane*2], u1 = Ps[lane*2+1];
      acc0.x += u0.x; acc0.y += u0.y; acc0.z += u0.z; acc0.w += u0.w;
      acc1.x += u1.x; acc1.y += u1.y; acc1.z += u1.z; acc1.w += u1.w;
    }
    v[0]=acc0.x; v[1]=acc0.y; v[2]=acc0.z; v[3]=acc0.w;
    v[4]=acc1.x; v[5]=acc1.y; v[6]=acc1.z; v[7]=acc1.w;
  }

  for (int rnd = 0; rnd < kTopK; ++rnd) {
    float bv = v[0];
    int   bi = lane * 8;
#pragma unroll
    for (int r = 1; r < 8; ++r) {
      if (v[r] > bv) { bv = v[r]; bi = lane * 8 + r; }
    }
#pragma unroll
    for (int off = 32; off >= 1; off >>= 1) {
      float ov = __shfl_xor(bv, off);
      int   oi = __shfl_xor(bi, off);
      if (ov > bv || (ov == bv && oi < bi)) { bv = ov; bi = oi; }
    }
    if (lane == 0) out[bt * kTopK + rnd] = bi;
#pragma unroll
    for (int r = 0; r < 8; ++r) {
      if (lane * 8 + r == bi) v[r] = -INFINITY;
    }
  }
}

// ============ fallback: round-1 single kernel (ws too small / unexpected shape) ============
__global__ __launch_bounds__(512, 1) void sparse_attn_topk_fallback(
    const float* __restrict__ x, const float* __restrict__ flat, int* __restrict__ out)
{
  __shared__ float4 wk4[kDIn];
  __shared__ float4 wq4[kDIn];
  __shared__ float4 Ks[kN];
  __shared__ float4 Qs[kN];
  __shared__ float  Ms[kN];
  __shared__ float  Rl[kN];
  __shared__ float  As[kN];

  const int tid = threadIdx.x;
  const int bt  = blockIdx.x;

  if (tid < 64)       wk4[tid]      = reinterpret_cast<const float4*>(flat)[tid];
  else if (tid < 128) wq4[tid - 64] = reinterpret_cast<const float4*>(flat)[tid];
  __syncthreads();

  const float* xr = x + ((size_t)bt * kN + tid) * kDIn;
  float k0=0.f,k1=0.f,k2=0.f,k3=0.f, q0=0.f,q1=0.f,q2=0.f,q3=0.f;
#pragma unroll
  for (int c = 0; c < kDIn; ++c) {
    float xv = xr[c];
    float4 a = wk4[c];
    float4 b = wq4[c];
    k0 = fmaf(xv, a.x, k0); k1 = fmaf(xv, a.y, k1);
    k2 = fmaf(xv, a.z, k2); k3 = fmaf(xv, a.w, k3);
    q0 = fmaf(xv, b.x, q0); q1 = fmaf(xv, b.y, q1);
    q2 = fmaf(xv, b.z, q2); q3 = fmaf(xv, b.w, q3);
  }
  Ks[tid] = make_float4(k0, k1, k2, k3);
  Qs[tid] = make_float4(q0, q1, q2, q3);
  __syncthreads();

  float m = -INFINITY;
#pragma unroll 8
  for (int j = 0; j < kN; ++j) {
    float4 qj = Qs[j];
    float h = fmaf(k0, qj.x, fmaf(k1, qj.y, fmaf(k2, qj.z, k3 * qj.w)));
    m = fmaxf(m, h);
  }
  float l = 0.f;
#pragma unroll 8
  for (int j = 0; j < kN; ++j) {
    float4 qj = Qs[j];
    float h = fmaf(k0, qj.x, fmaf(k1, qj.y, fmaf(k2, qj.z, k3 * qj.w)));
    l += exp2f(CEXP * (h - m));
  }
  Ms[tid] = m;
  Rl[tid] = 1.0f / l;
  __syncthreads();

  float acc = 0.f;
#pragma unroll 8
  for (int i = 0; i < kN; ++i) {
    float4 ki = Ks[i];
    float h = fmaf(q0, ki.x, fmaf(q1, ki.y, fmaf(q2, ki.z, q3 * ki.w)));
    acc += exp2f(CEXP * (h - Ms[i])) * Rl[i];
  }
  As[tid] = acc;
  __syncthreads();

  if (tid < 64) {
    float v[8];
#pragma unroll
    for (int r = 0; r < 8; ++r) v[r] = As[tid * 8 + r];
    for (int rnd = 0; rnd < kTopK; ++rnd) {
      float bv = v[0];
      int   bi = tid * 8;
#pragma unroll
      for (int r = 1; r < 8; ++r)
        if (v[r] > bv) { bv = v[r]; bi = tid * 8 + r; }
#pragma unroll
      for (int off = 32; off >= 1; off >>= 1) {
        float ov = __shfl_xor(bv, off);
        int   oi = __shfl_xor(bi, off);
        if (ov > bv || (ov == bv && oi < bi)) { bv = ov; bi = oi; }
      }
      if (tid == 0) out[bt * kTopK + rnd] = bi;
#pragma unroll
      for (int r = 0; r < 8; ++r)
        if (tid * 8 + r == bi) v[r] = -INFINITY;
    }
  }
}

extern "C" void kernel_launch(void* const* d_in, const int* in_sizes, int n_in,
                              void* d_out, int out_size, void* d_ws, size_t ws_size,
                              hipStream_t stream) {
  const float* x    = (const float*)d_in[0];
  const float* flat = (const float*)d_in[1];
  int* out = (int*)d_out;
  const int n_bt = in_sizes[0] / (kN * kDIn);

  if (n_bt != kNBt || ws_size < kWsFloats * sizeof(float)) {
    sparse_attn_topk_fallback<<<n_bt, kN, 0, stream>>>(x, flat, out);
    return;
  }
  float* apart = (float*)d_ws;
  fused_attn_kernel<<<kNBt * 4, 512, 0, stream>>>(x, flat, apart);
  topk_kernel      <<<kNBt,      64, 0, stream>>>(apart, out);
}